// Round 7
// baseline (237.494 us; speedup 1.0000x reference)
//
#include <hip/hip_runtime.h>
#include <hip/hip_cooperative_groups.h>
#include <math.h>

#define EMBED 256
#define HEADS 8
#define PDIM  32
#define BATCH 2
#define SEQ   1728            // 12*12*12
#define NTOK  (BATCH*SEQ)     // 3456
#define NE    (NTOK*EMBED)    // 884736
#define NKT   (SEQ/64)        // 27 key tiles
#define LOG2E 1.44269504088896f
#define NBLK  432
#define NTHR  256

typedef __attribute__((ext_vector_type(8))) __bf16 bf16x8;
typedef __attribute__((ext_vector_type(4))) float  f32x4;
typedef unsigned short ushort_t;
typedef unsigned int   uint_t;

static __device__ __forceinline__ unsigned short f2bf_rne(float f) {
    union { float f; unsigned u; } x; x.f = f;
    unsigned r = x.u + 0x7fffu + ((x.u >> 16) & 1u);
    return (unsigned short)(r >> 16);
}
union v8cast { uint4 u; bf16x8 v; };

// split 8 floats into bf16 hi + bf16 lo residual, packed
static __device__ __forceinline__ void cvt8_hilo(const float f[8], bf16x8& hi, bf16x8& lo) {
    uint4 ph, pl;
    uint_t* phv = (uint_t*)&ph; uint_t* plv = (uint_t*)&pl;
    #pragma unroll
    for (int j = 0; j < 4; ++j) {
        const float f0 = f[2 * j], f1 = f[2 * j + 1];
        const uint_t u0 = __float_as_uint(f0) + 0x8000u;
        const uint_t u1 = __float_as_uint(f1) + 0x8000u;
        phv[j] = __builtin_amdgcn_perm(u1, u0, 0x07060302u);
        const float l0 = f0 - __uint_as_float(u0 & 0xFFFF0000u);
        const float l1 = f1 - __uint_as_float(u1 & 0xFFFF0000u);
        plv[j] = __builtin_amdgcn_perm(__float_as_uint(l1) + 0x8000u,
                                       __float_as_uint(l0) + 0x8000u, 0x07060302u);
    }
    v8cast ch; ch.u = ph; hi = ch.v;
    v8cast cl; cl.u = pl; lo = cl.v;
}

// ====================== device-side phase bodies (shared) ======================

// QKV wave tile: M=64, N=32, K=256, hi/lo bf16 MFMA.  wg in [0,1296).
static __device__ __forceinline__ void qkv_tile(
    int wg, int li, int quad,
    const float* __restrict__ x,
    const float* __restrict__ Wq, const float* __restrict__ bq,
    const float* __restrict__ Wk, const float* __restrict__ bk,
    const float* __restrict__ Wv, const float* __restrict__ bv,
    ushort_t* __restrict__ qg, ushort_t* __restrict__ kg, ushort_t* __restrict__ vg)
{
    const int z   = wg / 432;
    const int rem = wg - z * 432;
    const int my  = rem % 54, ny = rem / 54;
    const int m0  = my * 64, n0 = ny * 32;
    const float* __restrict__ W    = (z == 0) ? Wq : (z == 1) ? Wk : Wv;
    const float* __restrict__ bias = (z == 0) ? bq : (z == 1) ? bk : bv;

    const float* ap = x + (size_t)(m0 + li) * EMBED + quad * 8;

    f32x4 acc[4][2];
    #pragma unroll
    for (int mt = 0; mt < 4; ++mt)
        #pragma unroll
        for (int nt = 0; nt < 2; ++nt)
            acc[mt][nt] = (f32x4){0.f, 0.f, 0.f, 0.f};

    #pragma unroll 2
    for (int k0 = 0; k0 < EMBED; k0 += 32) {
        bf16x8 ah[4], al[4];
        #pragma unroll
        for (int mt = 0; mt < 4; ++mt) {
            float af[8];
            *(float4*)&af[0] = *(const float4*)(ap + (size_t)mt * 16 * EMBED + k0);
            *(float4*)&af[4] = *(const float4*)(ap + (size_t)mt * 16 * EMBED + k0 + 4);
            cvt8_hilo(af, ah[mt], al[mt]);
        }
        bf16x8 bh[2], bl[2];
        #pragma unroll
        for (int nt = 0; nt < 2; ++nt) {
            const int n = n0 + nt * 16 + li;
            const float* wp = W + (size_t)(k0 + quad * 8) * EMBED + n;
            float bf[8];
            #pragma unroll
            for (int jj = 0; jj < 8; ++jj) bf[jj] = wp[(size_t)jj * EMBED];
            cvt8_hilo(bf, bh[nt], bl[nt]);
        }
        #pragma unroll
        for (int mt = 0; mt < 4; ++mt)
            #pragma unroll
            for (int nt = 0; nt < 2; ++nt) {
                acc[mt][nt] = __builtin_amdgcn_mfma_f32_16x16x32_bf16(ah[mt], bh[nt], acc[mt][nt], 0, 0, 0);
                acc[mt][nt] = __builtin_amdgcn_mfma_f32_16x16x32_bf16(al[mt], bh[nt], acc[mt][nt], 0, 0, 0);
                acc[mt][nt] = __builtin_amdgcn_mfma_f32_16x16x32_bf16(ah[mt], bl[nt], acc[mt][nt], 0, 0, 0);
            }
    }

    const int b = m0 / SEQ;          // 64-row tile never straddles batch
    const int sbase = m0 - b * SEQ;

    if (z <= 1) {
        ushort_t* __restrict__ dst = z ? kg : qg;
        #pragma unroll
        for (int nt = 0; nt < 2; ++nt) {
            const int gcol = n0 + nt * 16 + li;
            const int h = gcol >> 5, p = gcol & 31;
            const float bb = bias[gcol];
            ushort_t* base = dst + ((size_t)(b * HEADS + h) * SEQ) * PDIM + p;
            #pragma unroll
            for (int mt = 0; mt < 4; ++mt)
                #pragma unroll
                for (int r = 0; r < 4; ++r) {
                    const int s = sbase + mt * 16 + quad * 4 + r;
                    base[(size_t)s * PDIM] = f2bf_rne(acc[mt][nt][r] + bb);
                }
        }
    } else {
        #pragma unroll
        for (int nt = 0; nt < 2; ++nt) {
            const int gcol = n0 + nt * 16 + li;
            const int h = gcol >> 5, p = gcol & 31;
            const float bb = bias[gcol];
            ushort_t* base = vg + ((size_t)(b * HEADS + h) * PDIM + p) * SEQ;
            #pragma unroll
            for (int mt = 0; mt < 4; ++mt) {
                const int s0 = sbase + mt * 16 + quad * 4;
                ushort4 wv4;
                wv4.x = f2bf_rne(acc[mt][nt][0] + bb);
                wv4.y = f2bf_rne(acc[mt][nt][1] + bb);
                wv4.z = f2bf_rne(acc[mt][nt][2] + bb);
                wv4.w = f2bf_rne(acc[mt][nt][3] + bb);
                *(ushort4*)&base[s0] = wv4;
            }
        }
    }
}

// out-proj wave tile: M=32, N=16, K=256, bf16 MFMA w/ fused Wo conversion.
// wg in [0,1728).
static __device__ __forceinline__ void outproj_tile(
    int wg, int li, int quad,
    const ushort_t* __restrict__ ag, const float* __restrict__ Wo,
    const float* __restrict__ bo, float* __restrict__ out)
{
    const int my = wg % 108, ny = wg / 108;
    const int m0 = my * 32, n0 = ny * 16;

    const ushort_t* aph = ag + (size_t)(m0 + li) * EMBED + quad * 8;

    f32x4 acc[2];
    acc[0] = (f32x4){0.f, 0.f, 0.f, 0.f};
    acc[1] = (f32x4){0.f, 0.f, 0.f, 0.f};

    #pragma unroll 2
    for (int k0 = 0; k0 < EMBED; k0 += 32) {
        const bf16x8 a0 = *(const bf16x8*)(aph + k0);
        const bf16x8 a1 = *(const bf16x8*)(aph + 16 * EMBED + k0);
        const float* wp = Wo + (size_t)(k0 + quad * 8) * EMBED + n0 + li;
        uint4 pb;
        uint_t* pbv = (uint_t*)&pb;
        #pragma unroll
        for (int j = 0; j < 4; ++j) {
            const uint_t u0 = __float_as_uint(wp[(size_t)(2 * j) * EMBED])     + 0x8000u;
            const uint_t u1 = __float_as_uint(wp[(size_t)(2 * j + 1) * EMBED]) + 0x8000u;
            pbv[j] = __builtin_amdgcn_perm(u1, u0, 0x07060302u);
        }
        v8cast cb; cb.u = pb;
        acc[0] = __builtin_amdgcn_mfma_f32_16x16x32_bf16(a0, cb.v, acc[0], 0, 0, 0);
        acc[1] = __builtin_amdgcn_mfma_f32_16x16x32_bf16(a1, cb.v, acc[1], 0, 0, 0);
    }

    const float bb = bo[n0 + li];
    #pragma unroll
    for (int mt = 0; mt < 2; ++mt)
        #pragma unroll
        for (int r = 0; r < 4; ++r) {
            const int row = m0 + mt * 16 + quad * 4 + r;
            out[(size_t)row * EMBED + n0 + li] = acc[mt][r] + bb;
        }
}

// ======================= single cooperative kernel =======================
// 432 blocks x 256 thr.  P1: QKV (1296 wave-tiles).  P2: attention, R5
// structure (block = 4 waves x 16 q-rows, K/V LDS-staged, 1 barrier/tile).
// P3: out-proj (1728 wave-tiles).  grid.sync() between phases.
// LDS 28 KB; launch_bounds(256,2) -> needs only 2 blocks/CU co-resident.
// ---------------------------------------------------------------------------
__global__ __launch_bounds__(256, 2) void fused_mhsa_kernel(
    const float* __restrict__ x,
    const float* __restrict__ Wq, const float* __restrict__ bq,
    const float* __restrict__ Wk, const float* __restrict__ bk,
    const float* __restrict__ Wv, const float* __restrict__ bv,
    const float* __restrict__ Wo, const float* __restrict__ bo,
    float* __restrict__ out,
    ushort_t* __restrict__ qg, ushort_t* __restrict__ kg,
    ushort_t* __restrict__ vg, ushort_t* __restrict__ ag)
{
    const int t    = threadIdx.x;
    const int lane = t & 63, w = t >> 6;
    const int li   = lane & 15, quad = lane >> 4;
    const int bid  = blockIdx.x;

    // ---- phase 1: QKV projection ----
    {
        const int wg = bid * 4 + w;        // wg in [0,1728); active < 1296
        if (wg < 1296)
            qkv_tile(wg, li, quad, x, Wq, bq, Wk, bk, Wv, bv, qg, kg, vg);
    }

    cooperative_groups::this_grid().sync();

    // ---- phase 2: flash attention (R5-verified structure) ----
    {
        const int bh = bid & 15, qt = bid >> 4;   // 432 = 27 x 16
        const int b  = bh >> 3, h = bh & 7;
        const int q0 = qt * 64 + w * 16;

        const ushort_t* __restrict__ qb = qg + (size_t)bh * SEQ * PDIM;
        const ushort_t* __restrict__ kb = kg + (size_t)bh * SEQ * PDIM;
        const ushort_t* __restrict__ vb = vg + (size_t)bh * PDIM * SEQ;

        __shared__ ushort_t Ks[2][64][40];
        __shared__ ushort_t Vs[2][32][72];
        __shared__ ushort_t Ps[4][16][72];

        const bf16x8 qfrag = *(const bf16x8*)(qb + (size_t)(q0 + li) * PDIM + quad * 8);

        const int jk = w * 16 + (lane >> 2), ck = (lane & 3) * 8;
        const int pv = w * 8 + (lane >> 3),  cv = (lane & 7) * 8;
        const ushort_t* kgp = kb + (size_t)jk * PDIM + ck;
        const ushort_t* vgp = vb + (size_t)pv * SEQ + cv;

        f32x4 o0 = {0.f, 0.f, 0.f, 0.f};
        f32x4 o1 = {0.f, 0.f, 0.f, 0.f};
        float m_run = -__builtin_inff(), l_run = 0.f;

        uint4 kreg = *(const uint4*)(kgp);
        uint4 vreg = *(const uint4*)(vgp);

        for (int kt = 0; kt < NKT; ++kt) {
            const int p = kt & 1;
            *(uint4*)&Ks[p][jk][ck] = kreg;
            *(uint4*)&Vs[p][pv][cv] = vreg;
            __syncthreads();
            if (kt + 1 < NKT) {
                kreg = *(const uint4*)(kgp + (size_t)(kt + 1) * 64 * PDIM);
                vreg = *(const uint4*)(vgp + (kt + 1) * 64);
            }

            const f32x4 zero = {0.f, 0.f, 0.f, 0.f};
            f32x4 st[4];
            #pragma unroll
            for (int jt = 0; jt < 4; ++jt) {
                const bf16x8 kf = *(const bf16x8*)&Ks[p][jt * 16 + li][quad * 8];
                st[jt] = __builtin_amdgcn_mfma_f32_16x16x32_bf16(kf, qfrag, zero, 0, 0, 0);
            }

            float tm = st[0][0];
            #pragma unroll
            for (int jt = 0; jt < 4; ++jt)
                #pragma unroll
                for (int r = 0; r < 4; ++r) tm = fmaxf(tm, st[jt][r]);
            tm = fmaxf(tm, __shfl_xor(tm, 16));
            tm = fmaxf(tm, __shfl_xor(tm, 32));
            const float mnew  = fmaxf(m_run, tm);
            const float negml = -(mnew * LOG2E);

            float ps = 0.f;
            #pragma unroll
            for (int jt = 0; jt < 4; ++jt) {
                const float p0 = __builtin_amdgcn_exp2f(fmaf(st[jt][0], LOG2E, negml));
                const float p1 = __builtin_amdgcn_exp2f(fmaf(st[jt][1], LOG2E, negml));
                const float p2 = __builtin_amdgcn_exp2f(fmaf(st[jt][2], LOG2E, negml));
                const float p3 = __builtin_amdgcn_exp2f(fmaf(st[jt][3], LOG2E, negml));
                ps += (p0 + p1) + (p2 + p3);
                uint2 pw;
                pw.x = __builtin_amdgcn_perm(__float_as_uint(p1) + 0x8000u,
                                             __float_as_uint(p0) + 0x8000u, 0x07060302u);
                pw.y = __builtin_amdgcn_perm(__float_as_uint(p3) + 0x8000u,
                                             __float_as_uint(p2) + 0x8000u, 0x07060302u);
                *(uint2*)&Ps[w][li][16 * jt + 4 * quad] = pw;
            }
            ps += __shfl_xor(ps, 16);
            ps += __shfl_xor(ps, 32);

            const float alpha = __builtin_amdgcn_exp2f(fmaf(m_run, LOG2E, negml));
            l_run = fmaf(l_run, alpha, ps);
            m_run = mnew;

            float af[4];
            #pragma unroll
            for (int r = 0; r < 4; ++r) af[r] = __shfl(alpha, 4 * quad + r);
            #pragma unroll
            for (int r = 0; r < 4; ++r) { o0[r] *= af[r]; o1[r] *= af[r]; }

            const bf16x8 pa0 = *(const bf16x8*)&Ps[w][li][8 * quad];
            const bf16x8 pa1 = *(const bf16x8*)&Ps[w][li][32 + 8 * quad];
            const bf16x8 vf00 = *(const bf16x8*)&Vs[p][li][quad * 8];
            const bf16x8 vf01 = *(const bf16x8*)&Vs[p][16 + li][quad * 8];
            const bf16x8 vf10 = *(const bf16x8*)&Vs[p][li][32 + quad * 8];
            const bf16x8 vf11 = *(const bf16x8*)&Vs[p][16 + li][32 + quad * 8];
            o0 = __builtin_amdgcn_mfma_f32_16x16x32_bf16(pa0, vf00, o0, 0, 0, 0);
            o0 = __builtin_amdgcn_mfma_f32_16x16x32_bf16(pa1, vf10, o0, 0, 0, 0);
            o1 = __builtin_amdgcn_mfma_f32_16x16x32_bf16(pa0, vf01, o1, 0, 0, 0);
            o1 = __builtin_amdgcn_mfma_f32_16x16x32_bf16(pa1, vf11, o1, 0, 0, 0);
        }

        float linv[4];
        #pragma unroll
        for (int r = 0; r < 4; ++r) linv[r] = 1.0f / __shfl(l_run, 4 * quad + r);
        #pragma unroll
        for (int r = 0; r < 4; ++r) {
            const int s = q0 + 4 * quad + r;
            ushort_t* row = ag + ((size_t)(b * SEQ + s)) * EMBED + h * PDIM;
            row[li]      = f2bf_rne(o0[r] * linv[r]);
            row[16 + li] = f2bf_rne(o1[r] * linv[r]);
        }
    }

    cooperative_groups::this_grid().sync();

    // ---- phase 3: output projection ----
    outproj_tile(bid * 4 + w, li, quad, ag, Wo, bo, out);
}

// ======================= fallback kernels (R5, known-good) =======================
__global__ __launch_bounds__(64) void qkv_gemm_kernel(
    const float* __restrict__ x,
    const float* __restrict__ Wq, const float* __restrict__ bq,
    const float* __restrict__ Wk, const float* __restrict__ bk,
    const float* __restrict__ Wv, const float* __restrict__ bv,
    ushort_t* __restrict__ qo, ushort_t* __restrict__ ko, ushort_t* __restrict__ vt)
{
    const int lane = threadIdx.x, li = lane & 15, quad = lane >> 4;
    const int wg = (blockIdx.z * 8 + blockIdx.y) * 54 + blockIdx.x;
    // re-encode to qkv_tile's wg convention: z*432 + ny*54 + my
    qkv_tile(blockIdx.z * 432 + blockIdx.y * 54 + blockIdx.x, li, quad,
             x, Wq, bq, Wk, bk, Wv, bv, qo, ko, vt);
    (void)wg;
}

__global__ __launch_bounds__(256) void attn_kernel(
    const ushort_t* __restrict__ q, const ushort_t* __restrict__ k,
    const ushort_t* __restrict__ vt, ushort_t* __restrict__ aob)
{
    const int t    = threadIdx.x;
    const int lane = t & 63, w = t >> 6;
    const int li   = lane & 15, quad = lane >> 4;
    const int bh = blockIdx.y;
    const int b  = bh >> 3, h = bh & 7;
    const int q0 = blockIdx.x * 64 + w * 16;

    const ushort_t* __restrict__ qb = q  + (size_t)bh * SEQ * PDIM;
    const ushort_t* __restrict__ kb = k  + (size_t)bh * SEQ * PDIM;
    const ushort_t* __restrict__ vb = vt + (size_t)bh * PDIM * SEQ;

    __shared__ ushort_t Ks[2][64][40];
    __shared__ ushort_t Vs[2][32][72];
    __shared__ ushort_t Ps[4][16][72];

    const bf16x8 qfrag = *(const bf16x8*)(qb + (size_t)(q0 + li) * PDIM + quad * 8);

    const int jk = w * 16 + (lane >> 2), ck = (lane & 3) * 8;
    const int pv = w * 8 + (lane >> 3),  cv = (lane & 7) * 8;
    const ushort_t* kgp = kb + (size_t)jk * PDIM + ck;
    const ushort_t* vgp = vb + (size_t)pv * SEQ + cv;

    f32x4 o0 = {0.f, 0.f, 0.f, 0.f};
    f32x4 o1 = {0.f, 0.f, 0.f, 0.f};
    float m_run = -__builtin_inff(), l_run = 0.f;

    uint4 kreg = *(const uint4*)(kgp);
    uint4 vreg = *(const uint4*)(vgp);

    for (int kt = 0; kt < NKT; ++kt) {
        const int p = kt & 1;
        *(uint4*)&Ks[p][jk][ck] = kreg;
        *(uint4*)&Vs[p][pv][cv] = vreg;
        __syncthreads();
        if (kt + 1 < NKT) {
            kreg = *(const uint4*)(kgp + (size_t)(kt + 1) * 64 * PDIM);
            vreg = *(const uint4*)(vgp + (kt + 1) * 64);
        }

        const f32x4 zero = {0.f, 0.f, 0.f, 0.f};
        f32x4 st[4];
        #pragma unroll
        for (int jt = 0; jt < 4; ++jt) {
            const bf16x8 kf = *(const bf16x8*)&Ks[p][jt * 16 + li][quad * 8];
            st[jt] = __builtin_amdgcn_mfma_f32_16x16x32_bf16(kf, qfrag, zero, 0, 0, 0);
        }

        float tm = st[0][0];
        #pragma unroll
        for (int jt = 0; jt < 4; ++jt)
            #pragma unroll
            for (int r = 0; r < 4; ++r) tm = fmaxf(tm, st[jt][r]);
        tm = fmaxf(tm, __shfl_xor(tm, 16));
        tm = fmaxf(tm, __shfl_xor(tm, 32));
        const float mnew  = fmaxf(m_run, tm);
        const float negml = -(mnew * LOG2E);

        float ps = 0.f;
        #pragma unroll
        for (int jt = 0; jt < 4; ++jt) {
            const float p0 = __builtin_amdgcn_exp2f(fmaf(st[jt][0], LOG2E, negml));
            const float p1 = __builtin_amdgcn_exp2f(fmaf(st[jt][1], LOG2E, negml));
            const float p2 = __builtin_amdgcn_exp2f(fmaf(st[jt][2], LOG2E, negml));
            const float p3 = __builtin_amdgcn_exp2f(fmaf(st[jt][3], LOG2E, negml));
            ps += (p0 + p1) + (p2 + p3);
            uint2 pw;
            pw.x = __builtin_amdgcn_perm(__float_as_uint(p1) + 0x8000u,
                                         __float_as_uint(p0) + 0x8000u, 0x07060302u);
            pw.y = __builtin_amdgcn_perm(__float_as_uint(p3) + 0x8000u,
                                         __float_as_uint(p2) + 0x8000u, 0x07060302u);
            *(uint2*)&Ps[w][li][16 * jt + 4 * quad] = pw;
        }
        ps += __shfl_xor(ps, 16);
        ps += __shfl_xor(ps, 32);

        const float alpha = __builtin_amdgcn_exp2f(fmaf(m_run, LOG2E, negml));
        l_run = fmaf(l_run, alpha, ps);
        m_run = mnew;

        float af[4];
        #pragma unroll
        for (int r = 0; r < 4; ++r) af[r] = __shfl(alpha, 4 * quad + r);
        #pragma unroll
        for (int r = 0; r < 4; ++r) { o0[r] *= af[r]; o1[r] *= af[r]; }

        const bf16x8 pa0 = *(const bf16x8*)&Ps[w][li][8 * quad];
        const bf16x8 pa1 = *(const bf16x8*)&Ps[w][li][32 + 8 * quad];
        const bf16x8 vf00 = *(const bf16x8*)&Vs[p][li][quad * 8];
        const bf16x8 vf01 = *(const bf16x8*)&Vs[p][16 + li][quad * 8];
        const bf16x8 vf10 = *(const bf16x8*)&Vs[p][li][32 + quad * 8];
        const bf16x8 vf11 = *(const bf16x8*)&Vs[p][16 + li][32 + quad * 8];
        o0 = __builtin_amdgcn_mfma_f32_16x16x32_bf16(pa0, vf00, o0, 0, 0, 0);
        o0 = __builtin_amdgcn_mfma_f32_16x16x32_bf16(pa1, vf10, o0, 0, 0, 0);
        o1 = __builtin_amdgcn_mfma_f32_16x16x32_bf16(pa0, vf01, o1, 0, 0, 0);
        o1 = __builtin_amdgcn_mfma_f32_16x16x32_bf16(pa1, vf11, o1, 0, 0, 0);
    }

    float linv[4];
    #pragma unroll
    for (int r = 0; r < 4; ++r) linv[r] = 1.0f / __shfl(l_run, 4 * quad + r);
    #pragma unroll
    for (int r = 0; r < 4; ++r) {
        const int s = q0 + 4 * quad + r;
        ushort_t* row = aob + ((size_t)(b * SEQ + s)) * EMBED + h * PDIM;
        row[li]      = f2bf_rne(o0[r] * linv[r]);
        row[16 + li] = f2bf_rne(o1[r] * linv[r]);
    }
}

__global__ __launch_bounds__(64) void out_gemm_kernel(
    const ushort_t* __restrict__ a, const float* __restrict__ Wo,
    const float* __restrict__ bo, float* __restrict__ out)
{
    const int lane = threadIdx.x, li = lane & 15, quad = lane >> 4;
    outproj_tile(blockIdx.y * 108 + blockIdx.x, li, quad, a, Wo, bo, out);
}

// ---------------------------------------------------------------------------
extern "C" void kernel_launch(void* const* d_in, const int* in_sizes, int n_in,
                              void* d_out, int out_size, void* d_ws, size_t ws_size,
                              hipStream_t stream)
{
    const float* x  = (const float*)d_in[0];
    const float* Wq = (const float*)d_in[1];
    const float* bq = (const float*)d_in[2];
    const float* Wk = (const float*)d_in[3];
    const float* bk = (const float*)d_in[4];
    const float* Wv = (const float*)d_in[5];
    const float* bv = (const float*)d_in[6];
    const float* Wo = (const float*)d_in[7];
    const float* bo = (const float*)d_in[8];
    float* out = (float*)d_out;

    ushort_t* ws = (ushort_t*)d_ws;
    ushort_t* qg = ws;                      // [b][h][s][p] bf16
    ushort_t* kg = qg + (size_t)NE;
    ushort_t* vg = kg + (size_t)NE;         // [b][h][p][s] bf16
    ushort_t* ag = vg + (size_t)NE;         // [b][s][h][p] bf16

    // occupancy guard: need >= 2 blocks/CU so 432 blocks are co-resident
    int maxb = 0;
    hipError_t qerr = hipOccupancyMaxActiveBlocksPerMultiprocessor(
        &maxb, (const void*)fused_mhsa_kernel, NTHR, 0);
    bool coop_done = false;
    if (qerr == hipSuccess && maxb >= 2) {
        void* args[] = { (void*)&x, (void*)&Wq, (void*)&bq, (void*)&Wk, (void*)&bk,
                         (void*)&Wv, (void*)&bv, (void*)&Wo, (void*)&bo, (void*)&out,
                         (void*)&qg, (void*)&kg, (void*)&vg, (void*)&ag };
        hipError_t lerr = hipLaunchCooperativeKernel((const void*)fused_mhsa_kernel,
                                                     dim3(NBLK), dim3(NTHR), args, 0, stream);
        coop_done = (lerr == hipSuccess);
    }
    if (!coop_done) {
        qkv_gemm_kernel<<<dim3(54, 8, 3), 64, 0, stream>>>(
            x, Wq, bq, Wk, bk, Wv, bv, qg, kg, vg);
        attn_kernel<<<dim3(SEQ / 64, BATCH * HEADS), 256, 0, stream>>>(qg, kg, vg, ag);
        out_gemm_kernel<<<dim3(108, 16), 64, 0, stream>>>(ag, Wo, bo, out);
    }
}

// Round 8
// 121.670 us; speedup vs baseline: 1.9519x; 1.9519x over previous
//
#include <hip/hip_runtime.h>
#include <math.h>

#define EMBED 256
#define HEADS 8
#define PDIM  32
#define BATCH 2
#define SEQ   1728            // 12*12*12
#define NTOK  (BATCH*SEQ)     // 3456
#define NE    (NTOK*EMBED)    // 884736
#define LOG2E 1.44269504088896f

typedef __attribute__((ext_vector_type(8))) __bf16 bf16x8;
typedef __attribute__((ext_vector_type(4))) float  f32x4;
typedef unsigned short ushort_t;
typedef unsigned int   uint_t;

static __device__ __forceinline__ unsigned short f2bf_rne(float f) {
    union { float f; unsigned u; } x; x.f = f;
    unsigned r = x.u + 0x7fffu + ((x.u >> 16) & 1u);
    return (unsigned short)(r >> 16);
}
union v8cast { uint4 u; bf16x8 v; };

// split 8 floats into bf16 hi + bf16 lo residual, packed
static __device__ __forceinline__ void cvt8_hilo(const float f[8], bf16x8& hi, bf16x8& lo) {
    uint4 ph, pl;
    uint_t* phv = (uint_t*)&ph; uint_t* plv = (uint_t*)&pl;
    #pragma unroll
    for (int j = 0; j < 4; ++j) {
        const float f0 = f[2 * j], f1 = f[2 * j + 1];
        const uint_t u0 = __float_as_uint(f0) + 0x8000u;
        const uint_t u1 = __float_as_uint(f1) + 0x8000u;
        phv[j] = __builtin_amdgcn_perm(u1, u0, 0x07060302u);
        const float l0 = f0 - __uint_as_float(u0 & 0xFFFF0000u);
        const float l1 = f1 - __uint_as_float(u1 & 0xFFFF0000u);
        plv[j] = __builtin_amdgcn_perm(__float_as_uint(l1) + 0x8000u,
                                       __float_as_uint(l0) + 0x8000u, 0x07060302u);
    }
    v8cast ch; ch.u = ph; hi = ch.v;
    v8cast cl; cl.u = pl; lo = cl.v;
}

// ---------------------------------------------------------------------------
// Kernel 1: QKV projection (R5-verified).  grid (54, 8, 3) x 64 (1 wave).
// Wave tile 64(M) x 32(N), K=256, fused fp32->bf16 hi/lo conversion.
// Q,K -> [b][h][s][p] bf16;  V -> [b][h][p][s] bf16 (transposed).
// ---------------------------------------------------------------------------
__global__ __launch_bounds__(64) void qkv_gemm_kernel(
    const float* __restrict__ x,
    const float* __restrict__ Wq, const float* __restrict__ bq,
    const float* __restrict__ Wk, const float* __restrict__ bk,
    const float* __restrict__ Wv, const float* __restrict__ bv,
    ushort_t* __restrict__ qo, ushort_t* __restrict__ ko, ushort_t* __restrict__ vt)
{
    const int lane = threadIdx.x, li = lane & 15, quad = lane >> 4;
    const int m0 = blockIdx.x * 64, n0 = blockIdx.y * 32, z = blockIdx.z;
    const float* __restrict__ W    = (z == 0) ? Wq : (z == 1) ? Wk : Wv;
    const float* __restrict__ bias = (z == 0) ? bq : (z == 1) ? bk : bv;

    const float* ap = x + (size_t)(m0 + li) * EMBED + quad * 8;

    f32x4 acc[4][2];
    #pragma unroll
    for (int mt = 0; mt < 4; ++mt)
        #pragma unroll
        for (int nt = 0; nt < 2; ++nt)
            acc[mt][nt] = (f32x4){0.f, 0.f, 0.f, 0.f};

    #pragma unroll 2
    for (int k0 = 0; k0 < EMBED; k0 += 32) {
        bf16x8 ah[4], al[4];
        #pragma unroll
        for (int mt = 0; mt < 4; ++mt) {
            float af[8];
            *(float4*)&af[0] = *(const float4*)(ap + (size_t)mt * 16 * EMBED + k0);
            *(float4*)&af[4] = *(const float4*)(ap + (size_t)mt * 16 * EMBED + k0 + 4);
            cvt8_hilo(af, ah[mt], al[mt]);
        }
        bf16x8 bh[2], bl[2];
        #pragma unroll
        for (int nt = 0; nt < 2; ++nt) {
            const int n = n0 + nt * 16 + li;
            const float* wp = W + (size_t)(k0 + quad * 8) * EMBED + n;
            float bf[8];
            #pragma unroll
            for (int jj = 0; jj < 8; ++jj) bf[jj] = wp[(size_t)jj * EMBED];
            cvt8_hilo(bf, bh[nt], bl[nt]);
        }
        #pragma unroll
        for (int mt = 0; mt < 4; ++mt)
            #pragma unroll
            for (int nt = 0; nt < 2; ++nt) {
                acc[mt][nt] = __builtin_amdgcn_mfma_f32_16x16x32_bf16(ah[mt], bh[nt], acc[mt][nt], 0, 0, 0);
                acc[mt][nt] = __builtin_amdgcn_mfma_f32_16x16x32_bf16(al[mt], bh[nt], acc[mt][nt], 0, 0, 0);
                acc[mt][nt] = __builtin_amdgcn_mfma_f32_16x16x32_bf16(ah[mt], bl[nt], acc[mt][nt], 0, 0, 0);
            }
    }

    const int b = m0 / SEQ;          // 64-row tile never straddles batch
    const int sbase = m0 - b * SEQ;

    if (z <= 1) {
        ushort_t* __restrict__ dst = z ? ko : qo;
        #pragma unroll
        for (int nt = 0; nt < 2; ++nt) {
            const int gcol = n0 + nt * 16 + li;
            const int h = gcol >> 5, p = gcol & 31;
            const float bb = bias[gcol];
            ushort_t* base = dst + ((size_t)(b * HEADS + h) * SEQ) * PDIM + p;
            #pragma unroll
            for (int mt = 0; mt < 4; ++mt)
                #pragma unroll
                for (int r = 0; r < 4; ++r) {
                    const int s = sbase + mt * 16 + quad * 4 + r;
                    base[(size_t)s * PDIM] = f2bf_rne(acc[mt][nt][r] + bb);
                }
        }
    } else {
        #pragma unroll
        for (int nt = 0; nt < 2; ++nt) {
            const int gcol = n0 + nt * 16 + li;
            const int h = gcol >> 5, p = gcol & 31;
            const float bb = bias[gcol];
            ushort_t* base = vt + ((size_t)(b * HEADS + h) * PDIM + p) * SEQ;
            #pragma unroll
            for (int mt = 0; mt < 4; ++mt) {
                const int s0 = sbase + mt * 16 + quad * 4;
                ushort4 wv4;
                wv4.x = f2bf_rne(acc[mt][nt][0] + bb);
                wv4.y = f2bf_rne(acc[mt][nt][1] + bb);
                wv4.z = f2bf_rne(acc[mt][nt][2] + bb);
                wv4.w = f2bf_rne(acc[mt][nt][3] + bb);
                *(ushort4*)&base[s0] = wv4;
            }
        }
    }
}

// ---------------------------------------------------------------------------
// Kernel 2: flash attention = R5 LDS staging + R4 split-K=2.
// grid (54, 16) x 256 (4 waves).  Wave w: pr=w>>1 (q-subtile), c=w&1 (chunk).
// Chunk c: c=0 -> key tiles 0..13, c=1 -> 14..26 (it=0 dummy).  The two
// pr-waves of chunk c cooperatively stage its 64-key K/V tile into
// single-buffered LDS (2 barriers/tile; next-tile loads in flight during
// compute).  Pair merge (m,l,O) through LDS (R4-verified); c==0 writes
// output bf16 [b][s][h][p].  LDS 33 KB -> 4 blocks/CU; ~13.5 waves/CU.
// ---------------------------------------------------------------------------
__global__ __launch_bounds__(256) void attn_kernel(
    const ushort_t* __restrict__ q, const ushort_t* __restrict__ k,
    const ushort_t* __restrict__ vt, ushort_t* __restrict__ aob)
{
    const int t    = threadIdx.x;
    const int lane = t & 63, w = t >> 6;
    const int li   = lane & 15, quad = lane >> 4;
    const int pr   = w >> 1;          // q-subtile within block
    const int c    = w & 1;           // key chunk
    const int bh = blockIdx.y;
    const int b  = bh >> 3, h = bh & 7;
    const int q0 = blockIdx.x * 32 + pr * 16;

    const ushort_t* __restrict__ qb = q  + (size_t)bh * SEQ * PDIM;
    const ushort_t* __restrict__ kb = k  + (size_t)bh * SEQ * PDIM;
    const ushort_t* __restrict__ vb = vt + (size_t)bh * PDIM * SEQ;

    __shared__ ushort_t Ks[2][64][40];   // [c][key][p]   80 B rows
    __shared__ ushort_t Vs[2][32][72];   // [c][p][key]  144 B rows
    __shared__ ushort_t Ps[4][16][72];   // per-wave P round-trip
    __shared__ float OS[2][16][32];
    __shared__ float mS[2][16], lS[2][16];

    const bf16x8 qfrag = *(const bf16x8*)(qb + (size_t)(q0 + li) * PDIM + quad * 8);

    // staging: chunk c staged by its two pr-waves (row-split by pr)
    const int jk = pr * 32 + (lane >> 1), ck = (lane & 1) * 8;
    const int pv = pr * 16 + (lane >> 2), cv = (lane & 3) * 8;
    const ushort_t* kgp = kb + (size_t)jk * PDIM + ck;
    const ushort_t* vgp = vb + (size_t)pv * SEQ + cv;

    f32x4 o0 = {0.f, 0.f, 0.f, 0.f};
    f32x4 o1 = {0.f, 0.f, 0.f, 0.f};
    float m_run = -__builtin_inff(), l_run = 0.f;

    const int kt0 = c ? 13 : 0;          // c=0: tiles 0..13; c=1: 14..26 (it0 dummy)

    uint4 kr0 = *(const uint4*)(kgp + (size_t)kt0 * 64 * PDIM);
    uint4 kr1 = *(const uint4*)(kgp + (size_t)kt0 * 64 * PDIM + 16);
    uint4 vr0 = *(const uint4*)(vgp + kt0 * 64);
    uint4 vr1 = *(const uint4*)(vgp + kt0 * 64 + 32);

    for (int it = 0; it < 14; ++it) {
        __syncthreads();                  // [A] prev compute's LDS reads done
        *(uint4*)&Ks[c][jk][ck]      = kr0;
        *(uint4*)&Ks[c][jk][ck + 16] = kr1;
        *(uint4*)&Vs[c][pv][cv]      = vr0;
        *(uint4*)&Vs[c][pv][cv + 32] = vr1;
        __syncthreads();                  // [B] stores visible
        if (it + 1 < 14) {
            const int tn = kt0 + it + 1;
            kr0 = *(const uint4*)(kgp + (size_t)tn * 64 * PDIM);
            kr1 = *(const uint4*)(kgp + (size_t)tn * 64 * PDIM + 16);
            vr0 = *(const uint4*)(vgp + tn * 64);
            vr1 = *(const uint4*)(vgp + tn * 64 + 32);
        }

        if (c == 0 || it > 0) {
            // ---- S^T = K * Q^T ----
            const f32x4 zero = {0.f, 0.f, 0.f, 0.f};
            f32x4 st[4];
            #pragma unroll
            for (int jt = 0; jt < 4; ++jt) {
                const bf16x8 kf = *(const bf16x8*)&Ks[c][jt * 16 + li][quad * 8];
                st[jt] = __builtin_amdgcn_mfma_f32_16x16x32_bf16(kf, qfrag, zero, 0, 0, 0);
            }

            // ---- online softmax (per-lane stats for query col i=li) ----
            float tm = st[0][0];
            #pragma unroll
            for (int jt = 0; jt < 4; ++jt)
                #pragma unroll
                for (int r = 0; r < 4; ++r) tm = fmaxf(tm, st[jt][r]);
            tm = fmaxf(tm, __shfl_xor(tm, 16));
            tm = fmaxf(tm, __shfl_xor(tm, 32));
            const float mnew  = fmaxf(m_run, tm);
            const float negml = -(mnew * LOG2E);

            float ps = 0.f;
            #pragma unroll
            for (int jt = 0; jt < 4; ++jt) {
                const float p0 = __builtin_amdgcn_exp2f(fmaf(st[jt][0], LOG2E, negml));
                const float p1 = __builtin_amdgcn_exp2f(fmaf(st[jt][1], LOG2E, negml));
                const float p2 = __builtin_amdgcn_exp2f(fmaf(st[jt][2], LOG2E, negml));
                const float p3 = __builtin_amdgcn_exp2f(fmaf(st[jt][3], LOG2E, negml));
                ps += (p0 + p1) + (p2 + p3);
                uint2 pw;
                pw.x = __builtin_amdgcn_perm(__float_as_uint(p1) + 0x8000u,
                                             __float_as_uint(p0) + 0x8000u, 0x07060302u);
                pw.y = __builtin_amdgcn_perm(__float_as_uint(p3) + 0x8000u,
                                             __float_as_uint(p2) + 0x8000u, 0x07060302u);
                *(uint2*)&Ps[w][li][16 * jt + 4 * quad] = pw;
            }
            ps += __shfl_xor(ps, 16);
            ps += __shfl_xor(ps, 32);

            const float alpha = __builtin_amdgcn_exp2f(fmaf(m_run, LOG2E, negml));
            l_run = fmaf(l_run, alpha, ps);
            m_run = mnew;

            float af[4];
            #pragma unroll
            for (int r = 0; r < 4; ++r) af[r] = __shfl(alpha, 4 * quad + r);
            #pragma unroll
            for (int r = 0; r < 4; ++r) { o0[r] *= af[r]; o1[r] *= af[r]; }

            // ---- O += P * V ----
            const bf16x8 pa0 = *(const bf16x8*)&Ps[w][li][8 * quad];
            const bf16x8 pa1 = *(const bf16x8*)&Ps[w][li][32 + 8 * quad];
            const bf16x8 vf00 = *(const bf16x8*)&Vs[c][li][quad * 8];
            const bf16x8 vf01 = *(const bf16x8*)&Vs[c][16 + li][quad * 8];
            const bf16x8 vf10 = *(const bf16x8*)&Vs[c][li][32 + quad * 8];
            const bf16x8 vf11 = *(const bf16x8*)&Vs[c][16 + li][32 + quad * 8];
            o0 = __builtin_amdgcn_mfma_f32_16x16x32_bf16(pa0, vf00, o0, 0, 0, 0);
            o0 = __builtin_amdgcn_mfma_f32_16x16x32_bf16(pa1, vf10, o0, 0, 0, 0);
            o1 = __builtin_amdgcn_mfma_f32_16x16x32_bf16(pa0, vf01, o1, 0, 0, 0);
            o1 = __builtin_amdgcn_mfma_f32_16x16x32_bf16(pa1, vf11, o1, 0, 0, 0);
        }
    }

    // ---- split-K merge within pr pair (R4-verified) ----
    __syncthreads();
    if (c == 1) {
        if (quad == 0) { mS[pr][li] = m_run; lS[pr][li] = l_run; }
        #pragma unroll
        for (int r = 0; r < 4; ++r) {
            OS[pr][4 * quad + r][li]      = o0[r];
            OS[pr][4 * quad + r][16 + li] = o1[r];
        }
    }
    __syncthreads();
    if (c == 0) {
        const float m1 = mS[pr][li], l1 = lS[pr][li];
        const float M  = fmaxf(m_run, m1);
        const float a0 = __builtin_amdgcn_exp2f((m_run - M) * LOG2E);
        const float a1 = __builtin_amdgcn_exp2f((m1    - M) * LOG2E);
        const float lt = a0 * l_run + a1 * l1;
        #pragma unroll
        for (int r = 0; r < 4; ++r) {
            const int row = 4 * quad + r;
            const float af0  = __shfl(a0, row);
            const float af1  = __shfl(a1, row);
            const float linv = 1.0f / __shfl(lt, row);
            const float v0 = (af0 * o0[r] + af1 * OS[pr][row][li])      * linv;
            const float v1 = (af0 * o1[r] + af1 * OS[pr][row][16 + li]) * linv;
            const int s = q0 + row;
            ushort_t* orow = aob + ((size_t)(b * SEQ + s)) * EMBED + h * PDIM;
            orow[li]      = f2bf_rne(v0);
            orow[16 + li] = f2bf_rne(v1);
        }
    }
}

// ---------------------------------------------------------------------------
// Kernel 3: output projection (R5-verified).  grid (54, 16) x 64.
// Wave tile 64(M) x 16(N), K=256, fused Wo fp32->bf16.  out fp32.
// ---------------------------------------------------------------------------
__global__ __launch_bounds__(64) void out_gemm_kernel(
    const ushort_t* __restrict__ a, const float* __restrict__ Wo,
    const float* __restrict__ bo, float* __restrict__ out)
{
    const int lane = threadIdx.x, li = lane & 15, quad = lane >> 4;
    const int m0 = blockIdx.x * 64, n0 = blockIdx.y * 16;

    const ushort_t* aph = a + (size_t)(m0 + li) * EMBED + quad * 8;

    f32x4 acc[4];
    #pragma unroll
    for (int mt = 0; mt < 4; ++mt) acc[mt] = (f32x4){0.f, 0.f, 0.f, 0.f};

    #pragma unroll 2
    for (int k0 = 0; k0 < EMBED; k0 += 32) {
        bf16x8 ah[4];
        #pragma unroll
        for (int mt = 0; mt < 4; ++mt)
            ah[mt] = *(const bf16x8*)(aph + (size_t)mt * 16 * EMBED + k0);
        const float* wp = Wo + (size_t)(k0 + quad * 8) * EMBED + n0 + li;
        uint4 pb;
        uint_t* pbv = (uint_t*)&pb;
        #pragma unroll
        for (int j = 0; j < 4; ++j) {
            const uint_t u0 = __float_as_uint(wp[(size_t)(2 * j) * EMBED])     + 0x8000u;
            const uint_t u1 = __float_as_uint(wp[(size_t)(2 * j + 1) * EMBED]) + 0x8000u;
            pbv[j] = __builtin_amdgcn_perm(u1, u0, 0x07060302u);
        }
        v8cast cb; cb.u = pb;
        #pragma unroll
        for (int mt = 0; mt < 4; ++mt)
            acc[mt] = __builtin_amdgcn_mfma_f32_16x16x32_bf16(ah[mt], cb.v, acc[mt], 0, 0, 0);
    }

    const float bb = bo[n0 + li];
    #pragma unroll
    for (int mt = 0; mt < 4; ++mt)
        #pragma unroll
        for (int r = 0; r < 4; ++r) {
            const int row = m0 + mt * 16 + quad * 4 + r;
            out[(size_t)row * EMBED + n0 + li] = acc[mt][r] + bb;
        }
}

// ---------------------------------------------------------------------------
extern "C" void kernel_launch(void* const* d_in, const int* in_sizes, int n_in,
                              void* d_out, int out_size, void* d_ws, size_t ws_size,
                              hipStream_t stream)
{
    const float* x  = (const float*)d_in[0];
    const float* Wq = (const float*)d_in[1];
    const float* bq = (const float*)d_in[2];
    const float* Wk = (const float*)d_in[3];
    const float* bk = (const float*)d_in[4];
    const float* Wv = (const float*)d_in[5];
    const float* bv = (const float*)d_in[6];
    const float* Wo = (const float*)d_in[7];
    const float* bo = (const float*)d_in[8];
    float* out = (float*)d_out;

    ushort_t* ws = (ushort_t*)d_ws;
    ushort_t* qg = ws;                      // [b][h][s][p] bf16
    ushort_t* kg = qg + (size_t)NE;
    ushort_t* vg = kg + (size_t)NE;         // [b][h][p][s] bf16
    ushort_t* ag = vg + (size_t)NE;         // [b][s][h][p] bf16

    qkv_gemm_kernel<<<dim3(54, 8, 3), 64, 0, stream>>>(
        x, Wq, bq, Wk, bk, Wv, bv, qg, kg, vg);
    attn_kernel<<<dim3(54, 16), 256, 0, stream>>>(qg, kg, vg, ag);
    out_gemm_kernel<<<dim3(54, 16), 64, 0, stream>>>(ag, Wo, bo, out);
}